// Round 1
// baseline (1390.989 us; speedup 1.0000x reference)
//
#include <hip/hip_runtime.h>
#include <hip/hip_bf16.h>

#define NN 100000
#define NE 1600000
// D_H = D_E = D_Q = 64, D_HID = 128, N_GRAPHS = 16

typedef unsigned short ushort8v __attribute__((ext_vector_type(8)));

__device__ __forceinline__ float b2f(unsigned short u) {
  return __uint_as_float(((unsigned)u) << 16);
}
__device__ __forceinline__ unsigned fkey(float f) {
  unsigned u = __float_as_uint(f);
  return (u & 0x80000000u) ? ~u : (u | 0x80000000u);
}
__device__ __forceinline__ float funkey(unsigned k) {
  unsigned u = (k & 0x80000000u) ? (k ^ 0x80000000u) : ~k;
  return __uint_as_float(u);
}

// Qg[g][j] = gate_b1[j] + sum_k q[g][k] * gate_w1[128+k][j]
__global__ void qproj_kernel(const float* __restrict__ q,
                             const float* __restrict__ gw1,
                             const float* __restrict__ gb1,
                             float* __restrict__ Qg) {
  int g = blockIdx.x, j = threadIdx.x;
  float acc = gb1[j];
  for (int k = 0; k < 64; ++k) acc += q[g * 64 + k] * gw1[(128 + k) * 128 + j];
  Qg[g * 128 + j] = acc;
}

// Node projections: [N x 64] @ [64 x 512] -> SRCP[N][256]=(Ga|Sa), DSTP[N][256]=(Gb|Sb), bf16.
// grid.y part: 0=Ga(gw1 r0-63->SRCP c0) 1=Sa(sw1 r0-63->SRCP c128)
//              2=Gb(gw1 r64-127->DSTP c0) 3=Sb(sw1 r64-127->DSTP c128)
__global__ __launch_bounds__(256) void nodeproj_kernel(
    const float* __restrict__ h, const float* __restrict__ gw1,
    const float* __restrict__ sw1, __hip_bfloat16* __restrict__ SRCP,
    __hip_bfloat16* __restrict__ DSTP) {
  __shared__ float hs[64][64];   // [k][n]
  __shared__ float Ws[64][128];  // [k][c]
  int part = blockIdx.y;
  const float* W = (part & 1) ? sw1 : gw1;
  int roff = (part >= 2) ? 64 : 0;
  __hip_bfloat16* outp = (part >= 2) ? DSTP : SRCP;
  int coff = (part & 1) ? 128 : 0;
  int n0 = blockIdx.x * 64;
  int t = threadIdx.x;

  {  // stage h tile transposed: hs[k][n]
    int n = t & 63, kc = t >> 6;
    int gn = n0 + n;
#pragma unroll
    for (int i = 0; i < 4; ++i) {
      int k = kc * 16 + i * 4;
      float4 hv = make_float4(0.f, 0.f, 0.f, 0.f);
      if (gn < NN) hv = *(const float4*)&h[gn * 64 + k];
      hs[k + 0][n] = hv.x; hs[k + 1][n] = hv.y;
      hs[k + 2][n] = hv.z; hs[k + 3][n] = hv.w;
    }
  }
  {  // stage W tile (rows roff..roff+63, all 128 cols), flat copy
    const float* Wb = W + roff * 128;
    float* wsf = &Ws[0][0];
#pragma unroll
    for (int i = 0; i < 8; ++i) {
      int flat = (i * 256 + t) * 4;
      *(float4*)&wsf[flat] = *(const float4*)&Wb[flat];
    }
  }
  __syncthreads();

  int tx = t & 31, ty = t >> 5;  // 8 nodes (ty*8..) x 4 cols (tx+32i)
  float acc[8][4] = {};
#pragma unroll 4
  for (int k = 0; k < 64; ++k) {
    float hn[8];
    *(float4*)&hn[0] = *(const float4*)&hs[k][ty * 8];
    *(float4*)&hn[4] = *(const float4*)&hs[k][ty * 8 + 4];
    float wv[4];
#pragma unroll
    for (int i = 0; i < 4; ++i) wv[i] = Ws[k][tx + 32 * i];
#pragma unroll
    for (int j = 0; j < 8; ++j)
#pragma unroll
      for (int i = 0; i < 4; ++i) acc[j][i] += hn[j] * wv[i];
  }
#pragma unroll
  for (int j = 0; j < 8; ++j) {
    int gn = n0 + ty * 8 + j;
    if (gn < NN) {
#pragma unroll
      for (int i = 0; i < 4; ++i)
        outp[(size_t)gn * 256 + coff + tx + 32 * i] = __float2bfloat16(acc[j][i]);
    }
  }
}

// Fused per-edge MLP: raw = sigmoid(gateMLP) * scoreMLP; atomicMax per dst.
__global__ __launch_bounds__(256) void edge_kernel(
    const float* __restrict__ efeat, const int* __restrict__ eidx,
    const int* __restrict__ ebat, const __hip_bfloat16* __restrict__ SRCP,
    const __hip_bfloat16* __restrict__ DSTP, const float* __restrict__ Qg,
    const float* __restrict__ sw1, const float* __restrict__ sb1,
    const float* __restrict__ gw2, const float* __restrict__ gb2,
    const float* __restrict__ sw2, const float* __restrict__ sb2,
    float* __restrict__ raw_out, unsigned int* __restrict__ nodemax) {
  __shared__ float Ws[64][128];  // score_w1 rows 128..191 (the e-part), f32
  int t = threadIdx.x;
  {
    float* wsf = &Ws[0][0];
#pragma unroll
    for (int i = 0; i < 8; ++i) {
      int flat = (i * 256 + t) * 4;
      *(float4*)&wsf[flat] = *(const float4*)&sw1[16384 + flat];
    }
  }
  __syncthreads();

  int ee = blockIdx.x * 256 + t;  // NE % 256 == 0, no tail
  int src = eidx[ee];
  int dst = eidx[NE + ee];
  int g = ebat[ee];

  float er[64];
  const float* ep = efeat + (size_t)ee * 64;
#pragma unroll
  for (int i = 0; i < 16; ++i) *(float4*)&er[i * 4] = *(const float4*)&ep[i * 4];

  const unsigned short* srow = (const unsigned short*)SRCP + (size_t)src * 256;
  const unsigned short* drow = (const unsigned short*)DSTP + (size_t)dst * 256;
  const float* qrow = Qg + g * 128;

  float gacc = 0.f, sacc = 0.f;
#pragma unroll 1
  for (int jb = 0; jb < 4; ++jb) {
    int c0 = jb * 32;
    // batch the bf16 gathers 64B/stream so every L1 line is fully consumed
    ushort8v gaP[4], gbP[4], saP[4], sbP[4];
#pragma unroll
    for (int i = 0; i < 4; ++i) {
      gaP[i] = *(const ushort8v*)&srow[c0 + i * 8];
      gbP[i] = *(const ushort8v*)&drow[c0 + i * 8];
      saP[i] = *(const ushort8v*)&srow[128 + c0 + i * 8];
      sbP[i] = *(const ushort8v*)&drow[128 + c0 + i * 8];
    }
#pragma unroll
    for (int jc = 0; jc < 8; ++jc) {
      const int c = c0 + jc * 4;
      float4 qg = *(const float4*)&qrow[c];
      float4 g2 = *(const float4*)&gw2[c];
      float4 b1 = *(const float4*)&sb1[c];
      float4 s2 = *(const float4*)&sw2[c];
      float qgv[4] = {qg.x, qg.y, qg.z, qg.w};
      float b1v[4] = {b1.x, b1.y, b1.z, b1.w};
      float hg[4], es[4];
#pragma unroll
      for (int i = 0; i < 4; ++i) {
        int el = jc * 4 + i;
        float ga = b2f(gaP[el >> 3][el & 7]);
        float gb = b2f(gbP[el >> 3][el & 7]);
        float sa = b2f(saP[el >> 3][el & 7]);
        float sb = b2f(sbP[el >> 3][el & 7]);
        hg[i] = fmaxf(ga + gb + qgv[i], 0.f);
        es[i] = sa + sb + b1v[i];
      }
      gacc += hg[0] * g2.x + hg[1] * g2.y + hg[2] * g2.z + hg[3] * g2.w;
#pragma unroll
      for (int k = 0; k < 64; ++k) {
        float ek = er[k];
        float4 w = *(const float4*)&Ws[k][c];  // uniform addr -> LDS broadcast
        es[0] += ek * w.x; es[1] += ek * w.y;
        es[2] += ek * w.z; es[3] += ek * w.w;
      }
      sacc += fmaxf(es[0], 0.f) * s2.x + fmaxf(es[1], 0.f) * s2.y +
              fmaxf(es[2], 0.f) * s2.z + fmaxf(es[3], 0.f) * s2.w;
    }
  }
  float gate = 1.f / (1.f + __expf(-(gacc + gb2[0])));
  float raw = gate * (sacc + sb2[0]);
  raw_out[ee] = raw;
  atomicMax(&nodemax[dst], fkey(raw));
}

__global__ __launch_bounds__(256) void expsum_kernel(
    const float* __restrict__ raw, const int* __restrict__ eidx,
    const unsigned* __restrict__ nodemax, float* __restrict__ out,
    float* __restrict__ nodesum) {
  int ee = blockIdx.x * 256 + threadIdx.x;
  int dst = eidx[NE + ee];
  float m = funkey(nodemax[dst]);
  float ex = __expf(raw[ee] - m);
  out[ee] = ex;
  atomicAdd(&nodesum[dst], ex);
}

__global__ __launch_bounds__(256) void norm_kernel(
    const int* __restrict__ eidx, const float* __restrict__ nodesum,
    float* __restrict__ out) {
  int ee = blockIdx.x * 256 + threadIdx.x;
  int dst = eidx[NE + ee];
  out[ee] = out[ee] / fmaxf(nodesum[dst], 1e-9f);
}

extern "C" void kernel_launch(void* const* d_in, const int* in_sizes, int n_in,
                              void* d_out, int out_size, void* d_ws, size_t ws_size,
                              hipStream_t stream) {
  const float* h   = (const float*)d_in[0];
  const float* e   = (const float*)d_in[1];
  const float* q   = (const float*)d_in[2];
  const int* eidx  = (const int*)d_in[3];   // [2, NE] (src row, dst row)
  const int* ebat  = (const int*)d_in[4];
  const float* gw1 = (const float*)d_in[5];
  const float* gb1 = (const float*)d_in[6];
  const float* gw2 = (const float*)d_in[7];
  const float* gb2 = (const float*)d_in[8];
  const float* sw1 = (const float*)d_in[9];
  const float* sb1 = (const float*)d_in[10];
  const float* sw2 = (const float*)d_in[11];
  const float* sb2 = (const float*)d_in[12];
  float* out = (float*)d_out;

  char* ws = (char*)d_ws;
  // layout (bytes): SRCP 51.2MB | DSTP 51.2MB | Qg 8KB | raw 6.4MB | nmax 0.4MB | nsum 0.4MB
  __hip_bfloat16* SRCP = (__hip_bfloat16*)ws;
  __hip_bfloat16* DSTP = (__hip_bfloat16*)(ws + 51200000);
  float* Qg      = (float*)(ws + 102400000);
  float* rawb    = (float*)(ws + 102400000 + 8192);
  unsigned* nmax = (unsigned*)(ws + 102400000 + 8192 + 6400000);
  float* nsum    = (float*)(ws + 102400000 + 8192 + 6400000 + 400000);

  hipMemsetAsync(nmax, 0, 800000, stream);  // key 0 == -inf sentinel; sums = 0.0f
  qproj_kernel<<<dim3(16), dim3(128), 0, stream>>>(q, gw1, gb1, Qg);
  nodeproj_kernel<<<dim3(1563, 4), dim3(256), 0, stream>>>(h, gw1, sw1, SRCP, DSTP);
  edge_kernel<<<dim3(NE / 256), dim3(256), 0, stream>>>(
      e, eidx, ebat, SRCP, DSTP, Qg, sw1, sb1, gw2, gb2, sw2, sb2, rawb, nmax);
  expsum_kernel<<<dim3(NE / 256), dim3(256), 0, stream>>>(rawb, eidx, nmax, out, nsum);
  norm_kernel<<<dim3(NE / 256), dim3(256), 0, stream>>>(eidx, nsum, out);
}

// Round 3
// 526.097 us; speedup vs baseline: 2.6440x; 2.6440x over previous
//
#include <hip/hip_runtime.h>
#include <hip/hip_bf16.h>

#define NN 100000
#define NE 1600000
// D_H = D_E = D_Q = 64, D_HID = 128, N_GRAPHS = 16

typedef __attribute__((ext_vector_type(8))) unsigned short ushort8v;
typedef __attribute__((ext_vector_type(8))) short short8v;
typedef __attribute__((ext_vector_type(4))) float f32x4;

__device__ __forceinline__ float b2f(unsigned short u) {
  return __uint_as_float(((unsigned)u) << 16);
}
// f32 -> bf16 bits, round-to-nearest-even
__device__ __forceinline__ short f2bs(float f) {
  unsigned u = __float_as_uint(f);
  unsigned r = (u + 0x7FFFu + ((u >> 16) & 1u)) >> 16;
  return (short)r;
}
__device__ __forceinline__ unsigned fkey(float f) {
  unsigned u = __float_as_uint(f);
  return (u & 0x80000000u) ? ~u : (u | 0x80000000u);
}
__device__ __forceinline__ float funkey(unsigned k) {
  unsigned u = (k & 0x80000000u) ? (k ^ 0x80000000u) : ~k;
  return __uint_as_float(u);
}

// Qg[g][j] = gate_b1[j] + sum_k q[g][k] * gate_w1[128+k][j]
__global__ void qproj_kernel(const float* __restrict__ q,
                             const float* __restrict__ gw1,
                             const float* __restrict__ gb1,
                             float* __restrict__ Qg) {
  int g = blockIdx.x, j = threadIdx.x;
  float acc = gb1[j];
  for (int k = 0; k < 64; ++k) acc += q[g * 64 + k] * gw1[(128 + k) * 128 + j];
  Qg[g * 128 + j] = acc;
}

// Node projections (unchanged, known-good): [N x 64] @ [64 x 512] -> bf16
// SRCP[N][256]=(Ga|Sa), DSTP[N][256]=(Gb|Sb)
__global__ __launch_bounds__(256) void nodeproj_kernel(
    const float* __restrict__ h, const float* __restrict__ gw1,
    const float* __restrict__ sw1, __hip_bfloat16* __restrict__ SRCP,
    __hip_bfloat16* __restrict__ DSTP) {
  __shared__ float hs[64][64];   // [k][n]
  __shared__ float Ws[64][128];  // [k][c]
  int part = blockIdx.y;
  const float* W = (part & 1) ? sw1 : gw1;
  int roff = (part >= 2) ? 64 : 0;
  __hip_bfloat16* outp = (part >= 2) ? DSTP : SRCP;
  int coff = (part & 1) ? 128 : 0;
  int n0 = blockIdx.x * 64;
  int t = threadIdx.x;

  {
    int n = t & 63, kc = t >> 6;
    int gn = n0 + n;
#pragma unroll
    for (int i = 0; i < 4; ++i) {
      int k = kc * 16 + i * 4;
      float4 hv = make_float4(0.f, 0.f, 0.f, 0.f);
      if (gn < NN) hv = *(const float4*)&h[gn * 64 + k];
      hs[k + 0][n] = hv.x; hs[k + 1][n] = hv.y;
      hs[k + 2][n] = hv.z; hs[k + 3][n] = hv.w;
    }
  }
  {
    const float* Wb = W + roff * 128;
    float* wsf = &Ws[0][0];
#pragma unroll
    for (int i = 0; i < 8; ++i) {
      int flat = (i * 256 + t) * 4;
      *(float4*)&wsf[flat] = *(const float4*)&Wb[flat];
    }
  }
  __syncthreads();

  int tx = t & 31, ty = t >> 5;
  float acc[8][4] = {};
#pragma unroll 4
  for (int k = 0; k < 64; ++k) {
    float hn[8];
    *(float4*)&hn[0] = *(const float4*)&hs[k][ty * 8];
    *(float4*)&hn[4] = *(const float4*)&hs[k][ty * 8 + 4];
    float wv[4];
#pragma unroll
    for (int i = 0; i < 4; ++i) wv[i] = Ws[k][tx + 32 * i];
#pragma unroll
    for (int j = 0; j < 8; ++j)
#pragma unroll
      for (int i = 0; i < 4; ++i) acc[j][i] += hn[j] * wv[i];
  }
#pragma unroll
  for (int j = 0; j < 8; ++j) {
    int gn = n0 + ty * 8 + j;
    if (gn < NN) {
#pragma unroll
      for (int i = 0; i < 4; ++i)
        outp[(size_t)gn * 256 + coff + tx + 32 * i] = __float2bfloat16(acc[j][i]);
    }
  }
}

// MFMA edge kernel: 256 edges/block, 4 waves, 64 edges/wave.
// score hidden = e@Ws1c (MFMA, B in regs) + sa[src] + sb[dst] + sb1 -> relu -> dot s2
// gate = sigmoid(sum relu(ga+gb+Qg) * g2)  (VALU, one edge per lane)
__global__ __launch_bounds__(256) void edge_kernel(
    const float* __restrict__ e, const int* __restrict__ eidx,
    const int* __restrict__ ebat, const __hip_bfloat16* __restrict__ SRCP,
    const __hip_bfloat16* __restrict__ DSTP, const float* __restrict__ Qg,
    const float* __restrict__ sw1, const float* __restrict__ sb1,
    const float* __restrict__ gw2, const float* __restrict__ gb2,
    const float* __restrict__ sw2, const float* __restrict__ sb2,
    float* __restrict__ raw_out, unsigned* __restrict__ nmax) {
  __shared__ float gateLDS[256];
  const int tid = threadIdx.x;
  const int w = tid >> 6, lane = tid & 63;
  const int qg = lane >> 4, cl = lane & 15;
  const int EB = blockIdx.x * 256 + w * 64;
  const unsigned short* SU = (const unsigned short*)SRCP;
  const unsigned short* DU = (const unsigned short*)DSTP;

  // B fragments: B[k][n] = sw1[(128+k)*128 + n] (e-part rows), bf16 in VGPRs.
  // frag (t, ks): col n = 16t + cl, k = ks*32 + qg*8 + j
  short8v Bf[8][2];
#pragma unroll
  for (int t = 0; t < 8; ++t)
#pragma unroll
    for (int ks = 0; ks < 2; ++ks) {
      short8v b;
#pragma unroll
      for (int j = 0; j < 8; ++j) {
        int k = ks * 32 + qg * 8 + j;
        b[j] = f2bs(sw1[(128 + k) * 128 + t * 16 + cl]);
      }
      Bf[t][ks] = b;
    }

  float sbv[8], s2v[8];
#pragma unroll
  for (int t = 0; t < 8; ++t) {
    sbv[t] = sb1[t * 16 + cl];
    s2v[t] = sw2[t * 16 + cl];
  }
  const float sb2v = sb2[0], gb2v = gb2[0];

  // ---- gate phase: lane handles edge EB + lane ----
  {
    int E = EB + lane;
    int src = eidx[E], dst = eidx[NE + E], g = ebat[E];
    const ushort8v* sr = (const ushort8v*)(SU + (size_t)src * 256);
    const ushort8v* dr = (const ushort8v*)(DU + (size_t)dst * 256);
    const float4* qv = (const float4*)(Qg + g * 128);
    const float4* w2 = (const float4*)gw2;
    float gacc = 0.f;
#pragma unroll
    for (int jo = 0; jo < 8; ++jo) {
      ushort8v ga = sr[jo], gb = dr[jo];
#pragma unroll
      for (int half = 0; half < 2; ++half) {
        float4 qq = qv[2 * jo + half];
        float4 ww = w2[2 * jo + half];
        float qa[4] = {qq.x, qq.y, qq.z, qq.w};
        float wa[4] = {ww.x, ww.y, ww.z, ww.w};
#pragma unroll
        for (int ii = 0; ii < 4; ++ii) {
          float x = b2f(ga[half * 4 + ii]) + b2f(gb[half * 4 + ii]) + qa[ii];
          gacc = fmaf(fmaxf(x, 0.f), wa[ii], gacc);
        }
      }
    }
    gateLDS[tid] = 1.f / (1.f + __expf(-(gacc + gb2v)));
  }
  __syncthreads();

  // ---- MFMA + epilogue: 4 row-tiles of 16 edges ----
#pragma unroll 1
  for (int rt = 0; rt < 4; ++rt) {
    // A fragments: row = cl (edge EB+rt*16+cl), k = ks*32 + qg*8 + j
    int arow = EB + rt * 16 + cl;
    const float* ap = e + (size_t)arow * 64 + qg * 8;
    f32x4 f0 = __builtin_nontemporal_load((const f32x4*)(ap + 0));
    f32x4 f1 = __builtin_nontemporal_load((const f32x4*)(ap + 4));
    f32x4 f2 = __builtin_nontemporal_load((const f32x4*)(ap + 32));
    f32x4 f3 = __builtin_nontemporal_load((const f32x4*)(ap + 36));
    short8v a0, a1;
    a0[0] = f2bs(f0.x); a0[1] = f2bs(f0.y); a0[2] = f2bs(f0.z); a0[3] = f2bs(f0.w);
    a0[4] = f2bs(f1.x); a0[5] = f2bs(f1.y); a0[6] = f2bs(f1.z); a0[7] = f2bs(f1.w);
    a1[0] = f2bs(f2.x); a1[1] = f2bs(f2.y); a1[2] = f2bs(f2.z); a1[3] = f2bs(f2.w);
    a1[4] = f2bs(f3.x); a1[5] = f2bs(f3.y); a1[6] = f2bs(f3.z); a1[7] = f2bs(f3.w);

    f32x4 acc[8];
#pragma unroll
    for (int t = 0; t < 8; ++t) {
      acc[t] = (f32x4){0.f, 0.f, 0.f, 0.f};
      acc[t] = __builtin_amdgcn_mfma_f32_16x16x32_bf16(a0, Bf[t][0], acc[t], 0, 0, 0);
      acc[t] = __builtin_amdgcn_mfma_f32_16x16x32_bf16(a1, Bf[t][1], acc[t], 0, 0, 0);
    }

    // epilogue: C layout col = cl, row = qg*4 + i (+rt*16)
    int srcv[4], dstv[4];
#pragma unroll
    for (int i = 0; i < 4; ++i) {
      int E = EB + rt * 16 + qg * 4 + i;
      srcv[i] = eidx[E];
      dstv[i] = eidx[NE + E];
    }
    float part[4] = {0.f, 0.f, 0.f, 0.f};
#pragma unroll
    for (int t = 0; t < 8; ++t) {
      int col = 128 + t * 16 + cl;
#pragma unroll
      for (int i = 0; i < 4; ++i) {
        float sa = b2f(SU[(size_t)srcv[i] * 256 + col]);
        float sb = b2f(DU[(size_t)dstv[i] * 256 + col]);
        float hv = acc[t][i] + sa + sb + sbv[t];
        part[i] = fmaf(fmaxf(hv, 0.f), s2v[t], part[i]);
      }
    }
#pragma unroll
    for (int m = 1; m < 16; m <<= 1)
#pragma unroll
      for (int i = 0; i < 4; ++i) part[i] += __shfl_xor(part[i], m, 64);

    if (cl < 4) {
      int r = rt * 16 + qg * 4 + cl;
      int E = EB + r;
      float p = (cl == 0) ? part[0] : (cl == 1) ? part[1] : (cl == 2) ? part[2] : part[3];
      int d   = (cl == 0) ? dstv[0] : (cl == 1) ? dstv[1] : (cl == 2) ? dstv[2] : dstv[3];
      float raw = gateLDS[w * 64 + r] * (p + sb2v);
      raw_out[E] = raw;
      atomicMax(&nmax[d], fkey(raw));
    }
  }
}

__global__ __launch_bounds__(256) void expsum_kernel(
    const float* __restrict__ raw, const int* __restrict__ eidx,
    const unsigned* __restrict__ nodemax, float* __restrict__ out,
    float* __restrict__ nodesum) {
  int ee = blockIdx.x * 256 + threadIdx.x;
  int dst = eidx[NE + ee];
  float m = funkey(nodemax[dst]);
  float ex = __expf(raw[ee] - m);
  out[ee] = ex;
  atomicAdd(&nodesum[dst], ex);
}

__global__ __launch_bounds__(256) void norm_kernel(
    const int* __restrict__ eidx, const float* __restrict__ nodesum,
    float* __restrict__ out) {
  int ee = blockIdx.x * 256 + threadIdx.x;
  int dst = eidx[NE + ee];
  out[ee] = out[ee] / fmaxf(nodesum[dst], 1e-9f);
}

extern "C" void kernel_launch(void* const* d_in, const int* in_sizes, int n_in,
                              void* d_out, int out_size, void* d_ws, size_t ws_size,
                              hipStream_t stream) {
  const float* h   = (const float*)d_in[0];
  const float* e   = (const float*)d_in[1];
  const float* q   = (const float*)d_in[2];
  const int* eidx  = (const int*)d_in[3];
  const int* ebat  = (const int*)d_in[4];
  const float* gw1 = (const float*)d_in[5];
  const float* gb1 = (const float*)d_in[6];
  const float* gw2 = (const float*)d_in[7];
  const float* gb2 = (const float*)d_in[8];
  const float* sw1 = (const float*)d_in[9];
  const float* sb1 = (const float*)d_in[10];
  const float* sw2 = (const float*)d_in[11];
  const float* sb2 = (const float*)d_in[12];
  float* out = (float*)d_out;

  char* ws = (char*)d_ws;
  __hip_bfloat16* SRCP = (__hip_bfloat16*)ws;
  __hip_bfloat16* DSTP = (__hip_bfloat16*)(ws + 51200000);
  float* Qg      = (float*)(ws + 102400000);
  float* rawb    = (float*)(ws + 102400000 + 8192);
  unsigned* nmax = (unsigned*)(ws + 102400000 + 8192 + 6400000);
  float* nsum    = (float*)(ws + 102400000 + 8192 + 6400000 + 400000);

  (void)hipMemsetAsync(nmax, 0, 800000, stream);  // nmax sentinel + nsum zeros
  qproj_kernel<<<dim3(16), dim3(128), 0, stream>>>(q, gw1, gb1, Qg);
  nodeproj_kernel<<<dim3(1563, 4), dim3(256), 0, stream>>>(h, gw1, sw1, SRCP, DSTP);
  edge_kernel<<<dim3(NE / 256), dim3(256), 0, stream>>>(
      e, eidx, ebat, SRCP, DSTP, Qg, sw1, sb1, gw2, gb2, sw2, sb2, rawb, nmax);
  expsum_kernel<<<dim3(NE / 256), dim3(256), 0, stream>>>(rawb, eidx, nmax, out, nsum);
  norm_kernel<<<dim3(NE / 256), dim3(256), 0, stream>>>(eidx, nsum, out);
}